// Round 10
// baseline (5260.622 us; speedup 1.0000x reference)
//
#include <hip/hip_runtime.h>
#include <cmath>

typedef float  f32x4  __attribute__((ext_vector_type(4)));
typedef float  f32x2  __attribute__((ext_vector_type(2)));
typedef __bf16 bf16x8 __attribute__((ext_vector_type(8)));

static constexpr int HN  = 1024;     // hidden
static constexpr int VN  = 32000;    // vocab
static constexpr int BN  = 8;        // batch
static constexpr int SN  = 256;      // seq
static constexpr int H4N = 4096;     // 4*H

// ---------------------------------------------------------------------------
// Blocked xp layout: xpB[t][wg][row16][b8], row = g*4+u for block wg's
// gate-row g*1024 + wg*4 + u. Each LSTM block reads ONE contiguous 512B
// chunk per step (8 cache lines, not 128).
// Gather: one block per t, all 8 batches; writes 128B-contiguous runs.
// ---------------------------------------------------------------------------
__global__ __launch_bounds__(256) void k_gather(const int* __restrict__ x,
    const float* __restrict__ w_ih0, const float* __restrict__ b_ih0,
    const float* __restrict__ b_hh0, float* __restrict__ xpB) {
  int t = blockIdx.x;
  __shared__ int toks[8];
  if (threadIdx.x < 8) toks[threadIdx.x] = x[threadIdx.x * SN + t];
  __syncthreads();
  int wgx = threadIdx.x;                   // this thread fills block wgx's rows
  for (int g = 0; g < 4; ++g) {
    float vals[4][8];
    #pragma unroll
    for (int u = 0; u < 4; ++u) {
      int row = g * 1024 + wgx * 4 + u;
      float bias = b_ih0[row] + b_hh0[row];
      const float* wr = w_ih0 + (size_t)row * VN;
      #pragma unroll
      for (int b = 0; b < 8; ++b) vals[u][b] = wr[toks[b]] + bias;
    }
    float* dst = xpB + (((size_t)t * 256 + wgx) * 16 + g * 4) * 8;
    #pragma unroll
    for (int u = 0; u < 4; ++u) {
      *(f32x4*)&dst[u * 8]     = *(f32x4*)&vals[u][0];
      *(f32x4*)&dst[u * 8 + 4] = *(f32x4*)&vals[u][4];
    }
  }
}

// ---------------------------------------------------------------------------
// Persistent LSTM layer (R5 protocol, proven best). 256 blocks x 256 thr,
// 1 block/CU (96.5KB LDS -> still 1/CU... enforced by barrier need: 160KB
// pool, next block needs 96.5KB > 63.5KB remaining -> guaranteed 1/CU).
//
// Exchange (per R5): h stores = relaxed agent atomics (write-through MALL);
// arrive = same-wave vmcnt(0) + relaxed fetch_add, 64 counters x 4 blocks;
// wait = 64 lanes relaxed spin; h reads = relaxed agent u64 loads (MALL).
// No invalidates ever -> wL/xp stay warm in L2.
//
// In-step changes vs R5: (1) ks-reduction via 5-level __shfl_xor butterfly
// (no LDS red phase, one less barrier); (2) xp read = one 512B contiguous
// chunk (blocked layout).
// ---------------------------------------------------------------------------
__global__ __launch_bounds__(256, 1) void k_lstm(
    const float* __restrict__ xpB,   // [S][256][16][8] blocked
    const float* __restrict__ w_hh,  // [4H][H]
    const float* __restrict__ h0,    // [B][H] (this layer)
    const float* __restrict__ c0,    // [B][H]
    float* __restrict__ hs,          // [S][B][H] out (also h exchange buffer)
    float* __restrict__ hn, float* __restrict__ cn,   // [B][H]
    unsigned* __restrict__ bar) {    // 64 counters, stride 32 uints
  __shared__ float wL[16][1024];          // 64KB, row = g*4+u, swizzled
  __shared__ float hL[8192];              // 32KB, chunk idx (k4*8+b)^((k4>>3)&7)
  __shared__ float gates[16][8];          // 512B

  const int tid = threadIdx.x;
  const int wg  = blockIdx.x;
  const int u0  = wg * 4;

  // ---- load weight slice into LDS once
  for (int it = 0; it < 16; ++it) {
    int g = it >> 2, u = it & 3;
    int k4 = tid;
    int k4s = k4 ^ ((k4 >> 3) & 7);       // swizzle within row
    f32x4 v = *(const f32x4*)&w_hh[((size_t)g * HN + u0 + u) * HN + k4 * 4];
    *(f32x4*)&wL[it][k4s * 4] = v;
  }
  float c_reg = 0.f;
  if (tid < 32) c_reg = c0[(tid & 7) * HN + u0 + (tid >> 3)];

  const int ks = tid & 31, rg = (tid >> 5) & 3, bg = tid >> 7;
  const int ksx = ks & 7;
  const int hb = tid & 7;                  // batch row this thread stages
  const int hk = tid >> 3;                 // u64 lane within row, 0..31
  const int ku = ks >> 2, kb = ks & 3;     // loader/writer mapping (ks<16)
  const int lrow = rg * 4 + ku, lb = bg * 4 + kb;
  __syncthreads();

  for (int t = 0; t < SN; ++t) {
    // ---- xp prefetch: one contiguous 512B chunk per block per step
    float xpv = 0.f;
    if (ks < 16) xpv = xpB[((size_t)t * 256 + wg) * 128 + lrow * 8 + lb];

    // ---- wait for step t-1 (64 lanes, one counter each, relaxed spin)
    if (t > 0) {
      if (tid < 64) {
        unsigned tgt = 4u * (unsigned)t;
        while (__hip_atomic_load(&bar[tid * 32], __ATOMIC_RELAXED,
                                 __HIP_MEMORY_SCOPE_AGENT) < tgt)
          __builtin_amdgcn_s_sleep(1);
      }
      __syncthreads();
    }

    // ---- load h(t-1) via agent-scope (MALL) u64 loads
    unsigned long long rv[16];
    if (t == 0) {
      const unsigned long long* s8 =
          (const unsigned long long*)h0 + (size_t)hb * 512 + hk;
      #pragma unroll
      for (int j = 0; j < 16; ++j) rv[j] = s8[j * 32];
    } else {
      const unsigned long long* hsrc8 =
          (const unsigned long long*)(hs + (size_t)(t - 1) * (BN * HN))
          + (size_t)hb * 512 + hk;
      #pragma unroll
      for (int j = 0; j < 16; ++j)
        rv[j] = __hip_atomic_load((unsigned long long*)(hsrc8 + j * 32),
                                  __ATOMIC_RELAXED, __HIP_MEMORY_SCOPE_AGENT);
    }
    #pragma unroll
    for (int j = 0; j < 16; ++j) {
      int k64 = hk + j * 32;               // u64 index within the row
      int k4 = k64 >> 1, half = k64 & 1;
      int idx = ((k4 << 3) | hb) ^ ((k4 >> 3) & 7);
      *(f32x2*)&hL[idx * 4 + half * 2] = __builtin_bit_cast(f32x2, rv[j]);
    }
    __syncthreads();

    // ---- gate matmul partials: 512 FMA, 64 ds_read_b128 per thread
    float acc[4][4] = {};
    #pragma unroll
    for (int j = 0; j < 8; ++j) {
      int k4 = ks * 8 + j;
      int k4s = k4 ^ ksx;
      f32x4 wv[4], hv[4];
      #pragma unroll
      for (int ri = 0; ri < 4; ++ri)
        wv[ri] = *(const f32x4*)&wL[rg * 4 + ri][k4s * 4];
      #pragma unroll
      for (int bi = 0; bi < 4; ++bi) {
        int idx = ((k4 << 3) | (bg * 4 + bi)) ^ ksx;
        hv[bi] = *(const f32x4*)&hL[idx * 4];
      }
      #pragma unroll
      for (int ri = 0; ri < 4; ++ri)
        #pragma unroll
        for (int bi = 0; bi < 4; ++bi)
          acc[ri][bi] += wv[ri][0]*hv[bi][0] + wv[ri][1]*hv[bi][1]
                       + wv[ri][2]*hv[bi][2] + wv[ri][3]*hv[bi][3];
    }

    // ---- butterfly reduce over ks (in-register, no LDS, no barrier)
    #pragma unroll
    for (int m = 1; m <= 16; m <<= 1)
      #pragma unroll
      for (int ri = 0; ri < 4; ++ri)
        #pragma unroll
        for (int bi = 0; bi < 4; ++bi)
          acc[ri][bi] += __shfl_xor(acc[ri][bi], m);

    // ---- gate assembly (ks<16: one (row,b) each; acc now fully reduced)
    if (ks < 16) gates[lrow][lb] = acc[ku][kb] + xpv;
    __syncthreads();

    // ---- nonlinearity + state update (32 threads: (u,b), all in wave 0)
    if (tid < 32) {
      int u = tid >> 3, b = tid & 7;
      float gi = gates[0 * 4 + u][b], gf = gates[1 * 4 + u][b];
      float gg = gates[2 * 4 + u][b], go = gates[3 * 4 + u][b];
      float si = 1.f / (1.f + expf(-gi));
      float sf = 1.f / (1.f + expf(-gf));
      float so = 1.f / (1.f + expf(-go));
      c_reg = sf * c_reg + si * tanhf(gg);
      float h = so * tanhf(c_reg);
      // write-through to coherence point (MALL)
      __hip_atomic_store(&hs[(size_t)t * (BN * HN) + b * HN + u0 + u], h,
                         __ATOMIC_RELAXED, __HIP_MEMORY_SCOPE_AGENT);
      if (t == SN - 1) {
        hn[b * HN + u0 + u] = h;
        cn[b * HN + u0 + u] = c_reg;
      }
    }

    // ---- arrive: tid0 shares wave 0 with the 32 h-store lanes, so
    //      vmcnt(0) orders those stores at the MALL before the add
    if (t != SN - 1) {
      if (tid == 0) {
        asm volatile("s_waitcnt vmcnt(0)" ::: "memory");
        __hip_atomic_fetch_add(&bar[(wg >> 2) * 32], 1u,
                               __ATOMIC_RELAXED, __HIP_MEMORY_SCOPE_AGENT);
      }
      __syncthreads();
    } else {
      __syncthreads();
    }
  }
}

// ---------------------------------------------------------------------------
// fp32 -> (bf16 hi, bf16 lo) split
// ---------------------------------------------------------------------------
__global__ __launch_bounds__(256) void k_split(const float* __restrict__ src,
    __bf16* __restrict__ hi, __bf16* __restrict__ lo) {
  int i = (blockIdx.x * 256 + threadIdx.x) * 4;
  f32x4 v = *(const f32x4*)&src[i];
  #pragma unroll
  for (int j = 0; j < 4; ++j) {
    __bf16 h = (__bf16)v[j];
    hi[i + j] = h;
    lo[i + j] = (__bf16)(v[j] - (float)h);
  }
}

// ---------------------------------------------------------------------------
// C[M=2048][N] = A[2048][1024] * Bsrc[N][1024]^T + bias1(+bias2), via
// 3-term bf16 split MFMA. 128x128 tile, BK=32, 4 waves.
// mode 1: logits (row t*8+b -> b*256+t). mode 2: blocked-xp output.
// ---------------------------------------------------------------------------
__global__ __launch_bounds__(256) void k_gemm(const __bf16* __restrict__ Ahi,
    const __bf16* __restrict__ Alo, const float* __restrict__ Bsrc,
    const float* __restrict__ bias1, const float* __restrict__ bias2,
    float* __restrict__ C, int Mt, int N, int mode) {
  __shared__ __bf16 sAh[128][32], sAl[128][32], sBh[128][32], sBl[128][32];
  int bid = blockIdx.x;
  int tn = bid / Mt, tm = bid % Mt;           // m-fastest: B-strip L2 reuse
  int tid = threadIdx.x, lane = tid & 63, wid = tid >> 6;
  int wr = wid >> 1, wc = wid & 1;
  f32x4 acc[4][4] = {};
  const size_t K = 1024;

  for (int kk = 0; kk < 1024; kk += 32) {
    __syncthreads();
    #pragma unroll
    for (int it = 0; it < 2; ++it) {
      int c = it * 256 + tid;                  // 512 chunks of bf16x8
      int r = c >> 2, k8 = (c & 3) * 8;
      size_t ga = (size_t)(tm * 128 + r) * K + kk + k8;
      *(bf16x8*)&sAh[r][k8] = *(const bf16x8*)&Ahi[ga];
      *(bf16x8*)&sAl[r][k8] = *(const bf16x8*)&Alo[ga];
      size_t gb = (size_t)(tn * 128 + r) * K + kk + k8;
      f32x4 x0 = *(const f32x4*)&Bsrc[gb];
      f32x4 x1 = *(const f32x4*)&Bsrc[gb + 4];
      bf16x8 bh, bl;
      #pragma unroll
      for (int j = 0; j < 4; ++j) {
        __bf16 h0 = (__bf16)x0[j]; bh[j]     = h0; bl[j]     = (__bf16)(x0[j] - (float)h0);
        __bf16 h1 = (__bf16)x1[j]; bh[4 + j] = h1; bl[4 + j] = (__bf16)(x1[j] - (float)h1);
      }
      *(bf16x8*)&sBh[r][k8] = bh;
      *(bf16x8*)&sBl[r][k8] = bl;
    }
    __syncthreads();

    int kq = (lane >> 4) * 8;
    bf16x8 ah[4], al[4], bh[4], bl[4];
    #pragma unroll
    for (int i = 0; i < 4; ++i) {
      int ra = wr * 64 + i * 16 + (lane & 15);
      ah[i] = *(const bf16x8*)&sAh[ra][kq];
      al[i] = *(const bf16x8*)&sAl[ra][kq];
      int rb = wc * 64 + i * 16 + (lane & 15);
      bh[i] = *(const bf16x8*)&sBh[rb][kq];
      bl[i] = *(const bf16x8*)&sBl[rb][kq];
    }
    #pragma unroll
    for (int i = 0; i < 4; ++i)
      #pragma unroll
      for (int j = 0; j < 4; ++j) {
        acc[i][j] = __builtin_amdgcn_mfma_f32_16x16x32_bf16(ah[i], bh[j], acc[i][j], 0, 0, 0);
        acc[i][j] = __builtin_amdgcn_mfma_f32_16x16x32_bf16(ah[i], bl[j], acc[i][j], 0, 0, 0);
        acc[i][j] = __builtin_amdgcn_mfma_f32_16x16x32_bf16(al[i], bh[j], acc[i][j], 0, 0, 0);
      }
  }

  // epilogue: C/D layout col=lane&15, row=(lane>>4)*4+reg (m89-verified)
  #pragma unroll
  for (int j = 0; j < 4; ++j) {
    int gcol = tn * 128 + wc * 64 + j * 16 + (lane & 15);
    float bv = bias1[gcol] + (bias2 ? bias2[gcol] : 0.f);
    #pragma unroll
    for (int i = 0; i < 4; ++i) {
      #pragma unroll
      for (int r = 0; r < 4; ++r) {
        int row = tm * 128 + wr * 64 + i * 16 + ((lane >> 4) << 2) + r;
        float val = acc[i][j][r] + bv;
        if (mode == 2) {
          int t = row >> 3, b = row & 7;
          int g = gcol >> 10, rem = gcol & 1023, wgx = rem >> 2, u = rem & 3;
          C[(((size_t)t * 256 + wgx) * 16 + g * 4 + u) * 8 + b] = val;
        } else {
          int orow = (mode == 1) ? ((row & 7) * 256 + (row >> 3)) : row;
          C[(size_t)orow * N + gcol] = val;
        }
      }
    }
  }
}

// ---------------------------------------------------------------------------
extern "C" void kernel_launch(void* const* d_in, const int* in_sizes, int n_in,
                              void* d_out, int out_size, void* d_ws, size_t ws_size,
                              hipStream_t stream) {
  (void)in_sizes; (void)n_in; (void)out_size; (void)ws_size;
  const int*   x     = (const int*)  d_in[0];
  const float* h0    = (const float*)d_in[1];
  const float* c0    = (const float*)d_in[2];
  const float* w_ih0 = (const float*)d_in[3];
  const float* w_hh0 = (const float*)d_in[4];
  const float* b_ih0 = (const float*)d_in[5];
  const float* b_hh0 = (const float*)d_in[6];
  const float* w_ih1 = (const float*)d_in[7];
  const float* w_hh1 = (const float*)d_in[8];
  const float* b_ih1 = (const float*)d_in[9];
  const float* b_hh1 = (const float*)d_in[10];
  const float* fc_w  = (const float*)d_in[11];
  const float* fc_b  = (const float*)d_in[12];
  float* out = (float*)d_out;
  float* ws  = (float*)d_ws;

  // ws layout (floats)
  float* xpB  = ws;                        // [S][256][16][8] = 8,388,608
  float* h1s  = ws + 8388608;              // [S][B][H]  = 2,097,152
  float* h2s  = ws + 10485760;             // 2,097,152
  __bf16* Ahi = (__bf16*)(ws + 12582912);  // 2048*1024 bf16
  __bf16* Alo = (__bf16*)(ws + 13631488);
  unsigned* bar = (unsigned*)(ws + 14680064); // 4096 uints: 2 layers x 64 x 32

  const size_t LOG = (size_t)2048 * VN;    // 65,536,000
  float* hn = out + LOG;                   // [2][8][1024]
  float* cn = out + LOG + 16384;           // [2][8][1024]

  hipMemsetAsync(bar, 0, 4096 * sizeof(unsigned), stream);

  k_gather<<<SN, 256, 0, stream>>>(x, w_ih0, b_ih0, b_hh0, xpB);

  // ---- layer 0 (persistent, 256 blocks = 256 CUs) ----
  k_lstm<<<256, 256, 0, stream>>>(xpB, w_hh0, h0, c0, h1s, hn, cn, bar);

  k_split<<<2048, 256, 0, stream>>>(h1s, Ahi, Alo);
  // xp1 = h1s @ w_ih1^T + biases, written BLOCKED (M=2048, N=4096, mode=2)
  k_gemm<<<16 * 32, 256, 0, stream>>>(Ahi, Alo, w_ih1, b_ih1, b_hh1, xpB,
                                      16, H4N, 2);

  // ---- layer 1 ----
  k_lstm<<<256, 256, 0, stream>>>(xpB, w_hh1, h0 + BN * HN, c0 + BN * HN,
                                  h2s, hn + BN * HN, cn + BN * HN, bar + 2048);

  k_split<<<2048, 256, 0, stream>>>(h2s, Ahi, Alo);
  // logits = h2s @ fc_w^T + fc_b  (M=2048, N=32000), row-permuted to b*S+t
  k_gemm<<<16 * 250, 256, 0, stream>>>(Ahi, Alo, fc_w, fc_b, nullptr, out,
                                       16, VN, 1);
}

// Round 11
// 4288.767 us; speedup vs baseline: 1.2266x; 1.2266x over previous
//
#include <hip/hip_runtime.h>
#include <cmath>

typedef float  f32x4  __attribute__((ext_vector_type(4)));
typedef float  f32x2  __attribute__((ext_vector_type(2)));
typedef __bf16 bf16x8 __attribute__((ext_vector_type(8)));

static constexpr int HN  = 1024;     // hidden
static constexpr int VN  = 32000;    // vocab
static constexpr int BN  = 8;        // batch
static constexpr int SN  = 256;     // seq
static constexpr int H4N = 4096;     // 4*H

// ---------------------------------------------------------------------------
// Blocked xp layout: xpB[t][wg][row16][b8], row = g*4+u for block wg's
// gate-row g*1024 + wg*4 + u. (R10-verified correct.)
// ---------------------------------------------------------------------------
__global__ __launch_bounds__(256) void k_gather(const int* __restrict__ x,
    const float* __restrict__ w_ih0, const float* __restrict__ b_ih0,
    const float* __restrict__ b_hh0, float* __restrict__ xpB) {
  int t = blockIdx.x;
  __shared__ int toks[8];
  if (threadIdx.x < 8) toks[threadIdx.x] = x[threadIdx.x * SN + t];
  __syncthreads();
  int wgx = threadIdx.x;                   // this thread fills block wgx's rows
  for (int g = 0; g < 4; ++g) {
    float vals[4][8];
    #pragma unroll
    for (int u = 0; u < 4; ++u) {
      int row = g * 1024 + wgx * 4 + u;
      float bias = b_ih0[row] + b_hh0[row];
      const float* wr = w_ih0 + (size_t)row * VN;
      #pragma unroll
      for (int b = 0; b < 8; ++b) vals[u][b] = wr[toks[b]] + bias;
    }
    float* dst = xpB + (((size_t)t * 256 + wgx) * 16 + g * 4) * 8;
    #pragma unroll
    for (int u = 0; u < 4; ++u) {
      *(f32x4*)&dst[u * 8]     = *(f32x4*)&vals[u][0];
      *(f32x4*)&dst[u * 8 + 4] = *(f32x4*)&vals[u][4];
    }
  }
}

// ---------------------------------------------------------------------------
// Persistent LSTM layer, TWO interleaved batch-chains (A: b0-3, B: b4-7).
// 256 blocks x 256 thr, 1 block/CU (88KB LDS -> next block can't co-reside).
// Block wg owns units [wg*4, wg*4+4).
//
// Exchange per chain = R5 protocol (best measured): sc1 write-through h
// stores from wave 0; same-wave vmcnt(0) + relaxed agent fetch_add on
// 64 counters x 4 blocks; 64-lane relaxed poll; sc1 (MALL) u64 h reads.
// No invalidates ever -> wL/xpB stay warm in L2.
//
// Interleave rationale: while this block computes chain B's phase, chain
// A's producers finish and its MALL round-trip completes -> A's next wait
// is short. Period ~ L + one phase instead of L + full compute.
// ---------------------------------------------------------------------------
__global__ __launch_bounds__(256, 1) void k_lstm(
    const float* __restrict__ xpB,   // [S][256][16][8] blocked
    const float* __restrict__ w_hh,  // [4H][H]
    const float* __restrict__ h0,    // [B][H] (this layer)
    const float* __restrict__ c0,    // [B][H]
    float* __restrict__ hs,          // [S][B][H] out (also h exchange buffer)
    float* __restrict__ hn, float* __restrict__ cn,   // [B][H]
    unsigned* __restrict__ bar) {    // [2 chains][64 ctr x 32 stride]
  __shared__ float wL[16][1024];          // 64KB, row = g*4+u, swizzled
  __shared__ float hL[4096];              // 16KB: 4 batches of one chain
  __shared__ float red[8][4][2][32];      // 8KB [rg*2+bg][ri][bi][ks]
  __shared__ float gates[16][4];          // 256B

  const int tid = threadIdx.x;
  const int wg  = blockIdx.x;
  const int u0  = wg * 4;

  // ---- load weight slice into LDS once (swizzled, R5 pattern)
  for (int it = 0; it < 16; ++it) {
    int g = it >> 2, u = it & 3;
    int k4 = tid;
    int k4s = k4 ^ ((k4 >> 3) & 7);
    f32x4 v = *(const f32x4*)&w_hh[((size_t)g * HN + u0 + u) * HN + k4 * 4];
    *(f32x4*)&wL[it][k4s * 4] = v;
  }
  // ---- c-state in registers: chain A and B (lanes tid<16 each hold one)
  float cstA = 0.f, cstB = 0.f;
  if (tid < 16) {
    int u = tid >> 2, b4 = tid & 3;
    cstA = c0[b4 * HN + u0 + u];
    cstB = c0[(b4 + 4) * HN + u0 + u];
  }

  const int ks = tid & 31, rg = (tid >> 5) & 3, bg = tid >> 7;
  const int ksx = ks & 7;
  const int lb4 = tid & 3, hk8 = tid >> 2;   // h-load mapping
  const int prow = tid >> 2, pb4 = tid & 3;  // reducer/xp mapping (tid<64)
  __syncthreads();

  for (int t = 0; t < SN; ++t) {
    #pragma unroll
    for (int c = 0; c < 2; ++c) {
      // ---- xp prefetch for this chain's 64 gate values (256B chunk)
      float xpv = 0.f;
      if (tid < 64)
        xpv = xpB[(((size_t)t * 256 + wg) * 16 + prow) * 8 + pb4 + c * 4];

      // ---- wait for this chain's step t-1 producers
      if (t > 0) {
        if (tid < 64) {
          const unsigned* ctr = &bar[c * 2048 + tid * 32];
          unsigned tgt = 4u * (unsigned)t;
          while (__hip_atomic_load(ctr, __ATOMIC_RELAXED,
                                   __HIP_MEMORY_SCOPE_AGENT) < tgt)
            __builtin_amdgcn_s_sleep(1);
        }
        __syncthreads();
      }

      // ---- load this chain's 4 h-rows (16KB) via sc1/MALL u64 loads
      unsigned long long rv[8];
      {
        int hb = lb4 + c * 4;
        if (t == 0) {
          const unsigned long long* s8 =
              (const unsigned long long*)h0 + (size_t)hb * 512 + hk8;
          #pragma unroll
          for (int j = 0; j < 8; ++j) rv[j] = s8[j * 64];
        } else {
          const unsigned long long* s8 =
              (const unsigned long long*)(hs + (size_t)(t - 1) * (BN * HN))
              + (size_t)hb * 512 + hk8;
          #pragma unroll
          for (int j = 0; j < 8; ++j)
            rv[j] = __hip_atomic_load((unsigned long long*)(s8 + j * 64),
                                      __ATOMIC_RELAXED,
                                      __HIP_MEMORY_SCOPE_AGENT);
        }
      }
      // ---- swizzle-stage into hL: idx = ((k4<<2)|b4) ^ ((k4>>3)&7)
      #pragma unroll
      for (int j = 0; j < 8; ++j) {
        int k64 = hk8 + j * 64;
        int k4 = k64 >> 1, half = k64 & 1;
        int idx = ((k4 << 2) | lb4) ^ ((k4 >> 3) & 7);
        *(f32x2*)&hL[idx * 4 + half * 2] = __builtin_bit_cast(f32x2, rv[j]);
      }
      __syncthreads();

      // ---- gate matmul partials: 256 FMA4, 32+16 LDS vec reads / thread
      float acc[4][2] = {};
      #pragma unroll
      for (int j = 0; j < 8; ++j) {
        int k4 = ks * 8 + j;
        int k4s = k4 ^ ksx;
        f32x4 wv[4], hv[2];
        #pragma unroll
        for (int ri = 0; ri < 4; ++ri)
          wv[ri] = *(const f32x4*)&wL[rg * 4 + ri][k4s * 4];
        #pragma unroll
        for (int bi = 0; bi < 2; ++bi) {
          int idx = ((k4 << 2) | (bg * 2 + bi)) ^ ksx;
          hv[bi] = *(const f32x4*)&hL[idx * 4];
        }
        #pragma unroll
        for (int ri = 0; ri < 4; ++ri)
          #pragma unroll
          for (int bi = 0; bi < 2; ++bi)
            acc[ri][bi] += wv[ri][0]*hv[bi][0] + wv[ri][1]*hv[bi][1]
                         + wv[ri][2]*hv[bi][2] + wv[ri][3]*hv[bi][3];
      }
      #pragma unroll
      for (int ri = 0; ri < 4; ++ri)
        #pragma unroll
        for (int bi = 0; bi < 2; ++bi)
          red[rg * 2 + bg][ri][bi][ks] = acc[ri][bi];
      __syncthreads();

      // ---- reduce over ks (64 threads: one per (gate-row16, b4))
      if (tid < 64) {
        int rrg = prow >> 2, ri = prow & 3, bbg = pb4 >> 1, bi = pb4 & 1;
        const float* rp = red[rrg * 2 + bbg][ri][bi];
        float s = 0.f;
        #pragma unroll
        for (int q = 0; q < 32; ++q) s += rp[(q + tid) & 31];  // bank-rotated
        gates[prow][pb4] = s + xpv;
      }
      __syncthreads();

      // ---- nonlinearity + state (16 lanes of wave 0: (u,b4))
      if (tid < 16) {
        int u = tid >> 2, b4 = tid & 3, b = b4 + c * 4;
        float gi = gates[0 * 4 + u][b4], gf = gates[1 * 4 + u][b4];
        float gg = gates[2 * 4 + u][b4], go = gates[3 * 4 + u][b4];
        float si = 1.f / (1.f + expf(-gi));
        float sf = 1.f / (1.f + expf(-gf));
        float so = 1.f / (1.f + expf(-go));
        float cc = (c == 0) ? cstA : cstB;
        cc = sf * cc + si * tanhf(gg);
        float h = so * tanhf(cc);
        if (c == 0) cstA = cc; else cstB = cc;
        // write-through to coherence point (MALL)
        __hip_atomic_store(&hs[(size_t)t * (BN * HN) + b * HN + u0 + u], h,
                           __ATOMIC_RELAXED, __HIP_MEMORY_SCOPE_AGENT);
        if (t == SN - 1) {
          hn[b * HN + u0 + u] = h;
          cn[b * HN + u0 + u] = cc;
        }
      }
      // ---- arrive: tid0 shares wave 0 with the 16 h-store lanes;
      //      vmcnt(0) orders those stores at the MALL before the add
      if (t != SN - 1 && tid == 0) {
        asm volatile("s_waitcnt vmcnt(0)" ::: "memory");
        __hip_atomic_fetch_add(&bar[c * 2048 + (wg >> 2) * 32], 1u,
                               __ATOMIC_RELAXED, __HIP_MEMORY_SCOPE_AGENT);
      }
      __syncthreads();   // gates/hL/red safe for next phase
    }
  }
}

// ---------------------------------------------------------------------------
// fp32 -> (bf16 hi, bf16 lo) split
// ---------------------------------------------------------------------------
__global__ __launch_bounds__(256) void k_split(const float* __restrict__ src,
    __bf16* __restrict__ hi, __bf16* __restrict__ lo) {
  int i = (blockIdx.x * 256 + threadIdx.x) * 4;
  f32x4 v = *(const f32x4*)&src[i];
  #pragma unroll
  for (int j = 0; j < 4; ++j) {
    __bf16 h = (__bf16)v[j];
    hi[i + j] = h;
    lo[i + j] = (__bf16)(v[j] - (float)h);
  }
}

// ---------------------------------------------------------------------------
// C[M=2048][N] = A[2048][1024] * Bsrc[N][1024]^T + bias1(+bias2), via
// 3-term bf16 split MFMA. 128x128 tile, BK=32, 4 waves.
// mode 1: logits (row t*8+b -> b*256+t). mode 2: blocked-xp output.
// ---------------------------------------------------------------------------
__global__ __launch_bounds__(256) void k_gemm(const __bf16* __restrict__ Ahi,
    const __bf16* __restrict__ Alo, const float* __restrict__ Bsrc,
    const float* __restrict__ bias1, const float* __restrict__ bias2,
    float* __restrict__ C, int Mt, int N, int mode) {
  __shared__ __bf16 sAh[128][32], sAl[128][32], sBh[128][32], sBl[128][32];
  int bid = blockIdx.x;
  int tn = bid / Mt, tm = bid % Mt;           // m-fastest: B-strip L2 reuse
  int tid = threadIdx.x, lane = tid & 63, wid = tid >> 6;
  int wr = wid >> 1, wc = wid & 1;
  f32x4 acc[4][4] = {};
  const size_t K = 1024;

  for (int kk = 0; kk < 1024; kk += 32) {
    __syncthreads();
    #pragma unroll
    for (int it = 0; it < 2; ++it) {
      int c = it * 256 + tid;                  // 512 chunks of bf16x8
      int r = c >> 2, k8 = (c & 3) * 8;
      size_t ga = (size_t)(tm * 128 + r) * K + kk + k8;
      *(bf16x8*)&sAh[r][k8] = *(const bf16x8*)&Ahi[ga];
      *(bf16x8*)&sAl[r][k8] = *(const bf16x8*)&Alo[ga];
      size_t gb = (size_t)(tn * 128 + r) * K + kk + k8;
      f32x4 x0 = *(const f32x4*)&Bsrc[gb];
      f32x4 x1 = *(const f32x4*)&Bsrc[gb + 4];
      bf16x8 bh, bl;
      #pragma unroll
      for (int j = 0; j < 4; ++j) {
        __bf16 h0 = (__bf16)x0[j]; bh[j]     = h0; bl[j]     = (__bf16)(x0[j] - (float)h0);
        __bf16 h1 = (__bf16)x1[j]; bh[4 + j] = h1; bl[4 + j] = (__bf16)(x1[j] - (float)h1);
      }
      *(bf16x8*)&sBh[r][k8] = bh;
      *(bf16x8*)&sBl[r][k8] = bl;
    }
    __syncthreads();

    int kq = (lane >> 4) * 8;
    bf16x8 ah[4], al[4], bh[4], bl[4];
    #pragma unroll
    for (int i = 0; i < 4; ++i) {
      int ra = wr * 64 + i * 16 + (lane & 15);
      ah[i] = *(const bf16x8*)&sAh[ra][kq];
      al[i] = *(const bf16x8*)&sAl[ra][kq];
      int rb = wc * 64 + i * 16 + (lane & 15);
      bh[i] = *(const bf16x8*)&sBh[rb][kq];
      bl[i] = *(const bf16x8*)&sBl[rb][kq];
    }
    #pragma unroll
    for (int i = 0; i < 4; ++i)
      #pragma unroll
      for (int j = 0; j < 4; ++j) {
        acc[i][j] = __builtin_amdgcn_mfma_f32_16x16x32_bf16(ah[i], bh[j], acc[i][j], 0, 0, 0);
        acc[i][j] = __builtin_amdgcn_mfma_f32_16x16x32_bf16(ah[i], bl[j], acc[i][j], 0, 0, 0);
        acc[i][j] = __builtin_amdgcn_mfma_f32_16x16x32_bf16(al[i], bh[j], acc[i][j], 0, 0, 0);
      }
  }

  // epilogue: C/D layout col=lane&15, row=(lane>>4)*4+reg (m89-verified)
  #pragma unroll
  for (int j = 0; j < 4; ++j) {
    int gcol = tn * 128 + wc * 64 + j * 16 + (lane & 15);
    float bv = bias1[gcol] + (bias2 ? bias2[gcol] : 0.f);
    #pragma unroll
    for (int i = 0; i < 4; ++i) {
      #pragma unroll
      for (int r = 0; r < 4; ++r) {
        int row = tm * 128 + wr * 64 + i * 16 + ((lane >> 4) << 2) + r;
        float val = acc[i][j][r] + bv;
        if (mode == 2) {
          int t = row >> 3, b = row & 7;
          int g = gcol >> 10, rem = gcol & 1023, wgx = rem >> 2, u = rem & 3;
          C[(((size_t)t * 256 + wgx) * 16 + g * 4 + u) * 8 + b] = val;
        } else {
          int orow = (mode == 1) ? ((row & 7) * 256 + (row >> 3)) : row;
          C[(size_t)orow * N + gcol] = val;
        }
      }
    }
  }
}

// ---------------------------------------------------------------------------
extern "C" void kernel_launch(void* const* d_in, const int* in_sizes, int n_in,
                              void* d_out, int out_size, void* d_ws, size_t ws_size,
                              hipStream_t stream) {
  (void)in_sizes; (void)n_in; (void)out_size; (void)ws_size;
  const int*   x     = (const int*)  d_in[0];
  const float* h0    = (const float*)d_in[1];
  const float* c0    = (const float*)d_in[2];
  const float* w_ih0 = (const float*)d_in[3];
  const float* w_hh0 = (const float*)d_in[4];
  const float* b_ih0 = (const float*)d_in[5];
  const float* b_hh0 = (const float*)d_in[6];
  const float* w_ih1 = (const float*)d_in[7];
  const float* w_hh1 = (const float*)d_in[8];
  const float* b_ih1 = (const float*)d_in[9];
  const float* b_hh1 = (const float*)d_in[10];
  const float* fc_w  = (const float*)d_in[11];
  const float* fc_b  = (const float*)d_in[12];
  float* out = (float*)d_out;
  float* ws  = (float*)d_ws;

  // ws layout (floats)
  float* xpB  = ws;                        // [S][256][16][8] = 8,388,608
  float* h1s  = ws + 8388608;              // [S][B][H]  = 2,097,152
  float* h2s  = ws + 10485760;             // 2,097,152
  __bf16* Ahi = (__bf16*)(ws + 12582912);  // 2048*1024 bf16
  __bf16* Alo = (__bf16*)(ws + 13631488);
  unsigned* bar = (unsigned*)(ws + 14680064); // 2 layers x 2 chains x 2048

  const size_t LOG = (size_t)2048 * VN;    // 65,536,000
  float* hn = out + LOG;                   // [2][8][1024]
  float* cn = out + LOG + 16384;           // [2][8][1024]

  hipMemsetAsync(bar, 0, 8192 * sizeof(unsigned), stream);

  k_gather<<<SN, 256, 0, stream>>>(x, w_ih0, b_ih0, b_hh0, xpB);

  // ---- layer 0 (persistent, 256 blocks = 256 CUs, 2 chains) ----
  k_lstm<<<256, 256, 0, stream>>>(xpB, w_hh0, h0, c0, h1s, hn, cn, bar);

  k_split<<<2048, 256, 0, stream>>>(h1s, Ahi, Alo);
  // xp1 = h1s @ w_ih1^T + biases, written BLOCKED (M=2048, N=4096, mode=2)
  k_gemm<<<16 * 32, 256, 0, stream>>>(Ahi, Alo, w_ih1, b_ih1, b_hh1, xpB,
                                      16, H4N, 2);

  // ---- layer 1 ----
  k_lstm<<<256, 256, 0, stream>>>(xpB, w_hh1, h0 + BN * HN, c0 + BN * HN,
                                  h2s, hn + BN * HN, cn + BN * HN, bar + 4096);

  k_split<<<2048, 256, 0, stream>>>(h2s, Ahi, Alo);
  // logits = h2s @ fc_w^T + fc_b  (M=2048, N=32000), row-permuted to b*S+t
  k_gemm<<<16 * 250, 256, 0, stream>>>(Ahi, Alo, fc_w, fc_b, nullptr, out,
                                       16, VN, 1);
}